// Round 4
// baseline (2399.425 us; speedup 1.0000x reference)
//
#include <hip/hip_runtime.h>
#include <hip/hip_bf16.h>
#include <stdint.h>

// Problem constants
#define E_TOTAL   800000
#define NNODES    50000
#define NNF       16
#define NEF       8
#define NGRAPHS   64
#define NPRED     8

#define CHUNK     50000
#define NCHUNK    16          // 16 * 50000 = 800000
#define MPAD      50048       // 391 * 128  (rows padded to tile)

typedef short v8s __attribute__((ext_vector_type(8)));
typedef float v4f __attribute__((ext_vector_type(4)));

// ---------------------------------------------------------------------------
// global -> LDS direct copy, 16B per lane. LDS dest must be wave-uniform;
// hardware writes base + lane*16. Global source is per-lane.
// ---------------------------------------------------------------------------
__device__ __forceinline__ void gload_lds16(const void* g, void* l) {
    __builtin_amdgcn_global_load_lds(
        (const __attribute__((address_space(1))) uint32_t*)g,
        (__attribute__((address_space(3))) uint32_t*)l,
        16, 0, 0);
}

// ---------------------------------------------------------------------------
// bf16 MFMA GEMM:  C[M,N] = act(A @ W + bias)
//   A  : bf16 [Mpad][Kpad] row-major (Mpad = gridDim.y*128, Kpad % 64 == 0)
//   Wt : bf16 [Npad][Kpad] (W transposed; Npad = gridDim.x*64)
//   bias: fp32 [Npad]
// Tile 128x64, BK=64, 4 waves (2x2), mfma_f32_16x16x32_bf16, 4x2 frags/wave.
// DOUBLE-BUFFERED: stage(kt+1) issued before compute(kt); one __syncthreads
// per iter (its implicit vmcnt(0) drain lands after the compute phase, so
// prefetch latency is hidden).
// LDS stored linearly (global_load_lds), 16B-chunk index XOR (row&7) applied
// on the GLOBAL source address; ds_read_b128 applies the same XOR -> no
// bank conflicts.
// MODE: 0 = store bf16, 1 = store fp32, 2 = atomic scatter-add into
//       aggr[dstIdx[row]*128 + col] (msg layer fused with aggregation).
// ---------------------------------------------------------------------------
template <int MODE, bool RELU>
__global__ __launch_bounds__(256)
void mfma_gemm(const __hip_bfloat16* __restrict__ A,
               const __hip_bfloat16* __restrict__ Wt,
               const float* __restrict__ bias,
               void* __restrict__ Cv,
               int Kpad, int ldc,
               const int* __restrict__ dstIdx, int validM)
{
    __shared__ __align__(16) char smem[49152];   // 2 x (A 16KB + W 8KB)

    const int tid  = threadIdx.x;
    const int lane = tid & 63;
    const int wave = tid >> 6;
    const int wrow = wave >> 1;   // 0..1
    const int wcol = wave & 1;    // 0..1

    const size_t KpadB = (size_t)Kpad * 2;
    const char* Ag = (const char*)A  + (size_t)blockIdx.y * 128 * KpadB;
    const char* Wg = (const char*)Wt + (size_t)blockIdx.x * 64  * KpadB;

    const int rsub = lane >> 3;   // 0..7 row within 8-row segment
    const int csub = lane & 7;    // 0..7 16B chunk within 128B row

    auto stage = [&](int kt, char* buf) {
        const size_t k0B = (size_t)kt * 128;     // 64 bf16 = 128 B
        char* bufW = buf + 16384;
#pragma unroll
        for (int q = 0; q < 4; ++q) {            // A: 16 segs of 1KB
            int seg = q * 4 + wave;
            int row = seg * 8 + rsub;            // 0..127
            int sc  = csub ^ (row & 7);
            gload_lds16(Ag + (size_t)row * KpadB + k0B + sc * 16, buf + seg * 1024);
        }
#pragma unroll
        for (int q = 0; q < 2; ++q) {            // W: 8 segs of 1KB
            int seg = q * 4 + wave;
            int row = seg * 8 + rsub;            // 0..63 (= output col)
            int sc  = csub ^ (row & 7);
            gload_lds16(Wg + (size_t)row * KpadB + k0B + sc * 16, bufW + seg * 1024);
        }
    };

    v4f acc[4][2];
#pragma unroll
    for (int i = 0; i < 4; ++i)
#pragma unroll
        for (int j = 0; j < 2; ++j) acc[i][j] = (v4f){0.f, 0.f, 0.f, 0.f};

    const int nk = Kpad >> 6;
    stage(0, smem);
    __syncthreads();                              // tile 0 visible

    for (int kt = 0; kt < nk; ++kt) {
        char* cur = smem + (kt & 1) * 24576;
        if (kt + 1 < nk)
            stage(kt + 1, smem + ((kt + 1) & 1) * 24576);   // prefetch (overlaps compute)
        char* curW = cur + 16384;
#pragma unroll
        for (int kb = 0; kb < 2; ++kb) {
            v8s a[4], b[2];
#pragma unroll
            for (int fi = 0; fi < 4; ++fi) {
                int r = wrow * 64 + fi * 16 + (lane & 15);
                int c = kb * 4 + (lane >> 4);
                a[fi] = *(const v8s*)(cur + r * 128 + ((c ^ (r & 7)) * 16));
            }
#pragma unroll
            for (int fj = 0; fj < 2; ++fj) {
                int r = wcol * 32 + fj * 16 + (lane & 15);
                int c = kb * 4 + (lane >> 4);
                b[fj] = *(const v8s*)(curW + r * 128 + ((c ^ (r & 7)) * 16));
            }
#pragma unroll
            for (int fi = 0; fi < 4; ++fi)
#pragma unroll
                for (int fj = 0; fj < 2; ++fj)
                    acc[fi][fj] = __builtin_amdgcn_mfma_f32_16x16x32_bf16(
                        a[fi], b[fj], acc[fi][fj], 0, 0, 0);
        }
        __syncthreads();   // drains prefetch vmcnt + protects cur before overwrite
    }

    // Epilogue. C/D layout: col = lane&15, row = (lane>>4)*4 + r  [m89/m91]
    const int rowbase = blockIdx.y * 128 + wrow * 64;
    const int colbase = blockIdx.x * 64 + wcol * 32;

    if (MODE == 2) {
        float* aggr = (float*)Cv;
#pragma unroll
        for (int fi = 0; fi < 4; ++fi) {
#pragma unroll
            for (int r = 0; r < 4; ++r) {
                int row = rowbase + fi * 16 + (lane >> 4) * 4 + r;
                if (row < validM) {
                    int dg = dstIdx[row] * 128;
#pragma unroll
                    for (int fj = 0; fj < 2; ++fj) {
                        int col = colbase + fj * 16 + (lane & 15);
                        atomicAdd(&aggr[dg + col], acc[fi][fj][r] + bias[col]);
                    }
                }
            }
        }
    } else {
#pragma unroll
        for (int fj = 0; fj < 2; ++fj) {
            int col = colbase + fj * 16 + (lane & 15);
            float bb = bias[col];
#pragma unroll
            for (int fi = 0; fi < 4; ++fi) {
#pragma unroll
                for (int r = 0; r < 4; ++r) {
                    int row = rowbase + fi * 16 + (lane >> 4) * 4 + r;
                    float v = acc[fi][fj][r] + bb;
                    if (RELU) v = fmaxf(v, 0.f);
                    if (MODE == 0)
                        ((__hip_bfloat16*)Cv)[(size_t)row * ldc + col] = __float2bfloat16(v);
                    else
                        ((float*)Cv)[(size_t)row * ldc + col] = v;
                }
            }
        }
    }
}

// ---------------------------------------------------------------------------
// Repack fp32 weight [K][N] row-major -> bf16 transposed padded [Npad][Kpad]
// ---------------------------------------------------------------------------
__global__ void repack_w(const float* __restrict__ src, __hip_bfloat16* __restrict__ dst,
                         int K, int N, int Kpad, int Npad)
{
    int t = blockIdx.x * 256 + threadIdx.x;
    if (t >= Kpad * Npad) return;
    int n = t / Kpad, k = t % Kpad;
    float v = (k < K && n < N) ? src[(size_t)k * N + n] : 0.f;
    dst[(size_t)n * Kpad + k] = __float2bfloat16(v);
}

__global__ void pad_bias(const float* __restrict__ src, float* __restrict__ dst,
                         int N, int Npad)
{
    int t = blockIdx.x * 256 + threadIdx.x;
    if (t < Npad) dst[t] = (t < N) ? src[t] : 0.f;
}

// ---------------------------------------------------------------------------
// tmp(bf16, [MPAD][64]) = [x[dst] | x[src] | edge_attr | 0-pad] for a chunk.
// ei[0:E] = src, ei[E:2E] = dst.
// ---------------------------------------------------------------------------
__global__ void build_tmp_bf16(const float* __restrict__ x,
                               const int* __restrict__ ei,
                               const float* __restrict__ ea,
                               __hip_bfloat16* __restrict__ tmp, int e0)
{
    int t = blockIdx.x * 256 + threadIdx.x;   // CHUNK*64 threads
    int e = t >> 6, f = t & 63;
    if (e >= CHUNK) return;
    int ge = e0 + e;
    float v = 0.f;
    if (f < NNF) {
        int dst = ei[E_TOTAL + ge];
        v = x[dst * NNF + f];
    } else if (f < 2 * NNF) {
        int src = ei[ge];
        v = x[src * NNF + (f - NNF)];
    } else if (f < 2 * NNF + NEF) {
        v = ea[(size_t)ge * NEF + (f - 2 * NNF)];
    }
    tmp[(size_t)e * 64 + f] = __float2bfloat16(v);
}

// ---------------------------------------------------------------------------
// aggr fp32 [MPAD][128] -> bf16 (rows >= NNODES forced to 0)
// ---------------------------------------------------------------------------
__global__ void cvt_aggr(const float* __restrict__ aggr, __hip_bfloat16* __restrict__ out)
{
    int t = blockIdx.x * 256 + threadIdx.x;   // MPAD*128 threads
    int row = t >> 7;
    float v = (row < NNODES) ? aggr[t] : 0.f;
    out[t] = __float2bfloat16(v);
}

// ---------------------------------------------------------------------------
__global__ void graph_starts_kernel(const int* __restrict__ batch,
                                    int* __restrict__ starts)
{
    int g = threadIdx.x;
    if (g > NGRAPHS) return;
    int lo = 0, hi = NNODES;
    while (lo < hi) {
        int mid = (lo + hi) >> 1;
        if (batch[mid] < g) lo = mid + 1; else hi = mid;
    }
    starts[g] = lo;
}

// ---------------------------------------------------------------------------
// Mean pool: node fp32 [MPAD][320] (valid cols 0..299) -> pooled [64][300]
// grid (64, 10); block 256 = 32 cols x 8 row-lanes
// ---------------------------------------------------------------------------
__global__ void pool_kernel(const float* __restrict__ node,
                            const int* __restrict__ starts,
                            float* __restrict__ pooled)
{
    __shared__ float red[8][32];
    int g   = blockIdx.x;
    int col = blockIdx.y * 32 + (threadIdx.x & 31);
    int rl  = threadIdx.x >> 5;   // 0..7
    int s = starts[g], e = starts[g + 1];
    float sum = 0.f;
    if (col < 300)
        for (int i = s + rl; i < e; i += 8) sum += node[(size_t)i * 320 + col];
    red[rl][threadIdx.x & 31] = sum;
    __syncthreads();
    if (rl == 0 && col < 300) {
        float tot = 0.f;
#pragma unroll
        for (int r = 0; r < 8; ++r) tot += red[r][threadIdx.x & 31];
        float cnt = (float)(e - s);
        pooled[g * 300 + col] = tot / fmaxf(cnt, 1.0f);
    }
}

// ---------------------------------------------------------------------------
__global__ void final_kernel(const float* __restrict__ pooled,
                             const float* __restrict__ lw,
                             const float* __restrict__ lb,
                             float* __restrict__ out)
{
    int t = threadIdx.x;          // 512 = 64 * 8
    int g = t / NPRED, p = t % NPRED;
    float s = lb[p];
    for (int k = 0; k < 300; ++k)
        s = fmaf(pooled[g * 300 + k], lw[k * NPRED + p], s);
    out[g * NPRED + p] = s;
}

// ---------------------------------------------------------------------------
extern "C" void kernel_launch(void* const* d_in, const int* in_sizes, int n_in,
                              void* d_out, int out_size, void* d_ws, size_t ws_size,
                              hipStream_t stream)
{
    const float* x     = (const float*)d_in[0];
    const int*   ei    = (const int*)d_in[1];
    const float* ea    = (const float*)d_in[2];
    const int*   batch = (const int*)d_in[3];
    const float* mw[4] = {(const float*)d_in[4], (const float*)d_in[6],
                          (const float*)d_in[8], (const float*)d_in[10]};
    const float* mb[4] = {(const float*)d_in[5], (const float*)d_in[7],
                          (const float*)d_in[9], (const float*)d_in[11]};
    const float* nw[4] = {(const float*)d_in[12], (const float*)d_in[14],
                          (const float*)d_in[16], (const float*)d_in[18]};
    const float* nb[4] = {(const float*)d_in[13], (const float*)d_in[15],
                          (const float*)d_in[17], (const float*)d_in[19]};
    const float* lw = (const float*)d_in[20];
    const float* lb = (const float*)d_in[21];
    float* out = (float*)d_out;

    char* ws = (char*)d_ws;
    size_t off = 0;
    auto alloc = [&](size_t bytes) -> void* {
        void* p = ws + off;
        off += (bytes + 255) & ~(size_t)255;
        return p;
    };

    // Persistent activations (bf16)
    __hip_bfloat16* hA = (__hip_bfloat16*)alloc((size_t)MPAD * 320 * 2);  // 32.0 MB
    __hip_bfloat16* hB = (__hip_bfloat16*)alloc((size_t)MPAD * 320 * 2);  // 32.0 MB
    // Union region U (64.1 MB): edge phase {aggr | aggrb | tmp}; node output
    // overlays the whole region (all three dead by the time L4-node writes).
    char* U = (char*)alloc((size_t)MPAD * 320 * 4);
    float*          aggr  = (float*)(U);                         // 25.6 MB
    __hip_bfloat16* aggrb = (__hip_bfloat16*)(U + 25624576);     // 12.8 MB
    __hip_bfloat16* tmp   = (__hip_bfloat16*)(U + 38436864);     //  6.4 MB
    float*          node  = (float*)(U);                         // 64.1 MB overlay

    // Weights (bf16, transposed, padded) + biases (fp32, padded)
    __hip_bfloat16* mwt[4]; __hip_bfloat16* nwt[4];
    float* mbp[4]; float* nbp[4];
    const int mK[4]  = {40, 300, 300, 300}, mN[4]  = {300, 300, 300, 128};
    const int mKp[4] = {64, 320, 320, 320}, mNp[4] = {320, 320, 320, 128};
    const int nK[4]  = {128, 300, 300, 300}, nN[4] = {300, 300, 300, 300};
    const int nKp[4] = {128, 320, 320, 320}, nNp[4] = {320, 320, 320, 320};
    for (int i = 0; i < 4; ++i) {
        mwt[i] = (__hip_bfloat16*)alloc((size_t)mNp[i] * mKp[i] * 2);
        nwt[i] = (__hip_bfloat16*)alloc((size_t)nNp[i] * nKp[i] * 2);
        mbp[i] = (float*)alloc(320 * 4);
        nbp[i] = (float*)alloc(320 * 4);
    }
    float* pooled = (float*)alloc(64 * 300 * 4);
    int*   starts = (int*)alloc(65 * 4);

    // ---- weight repack + bias pad + setup ----
    for (int i = 0; i < 4; ++i) {
        repack_w<<<(mKp[i] * mNp[i] + 255) / 256, 256, 0, stream>>>(
            mw[i], mwt[i], mK[i], mN[i], mKp[i], mNp[i]);
        repack_w<<<(nKp[i] * nNp[i] + 255) / 256, 256, 0, stream>>>(
            nw[i], nwt[i], nK[i], nN[i], nKp[i], nNp[i]);
        pad_bias<<<2, 256, 0, stream>>>(mb[i], mbp[i], mN[i], mNp[i]);
        pad_bias<<<2, 256, 0, stream>>>(nb[i], nbp[i], nN[i], nNp[i]);
    }
    hipMemsetAsync(aggr, 0, (size_t)MPAD * 128 * 4, stream);
    graph_starts_kernel<<<1, 128, 0, stream>>>(batch, starts);

    const dim3 gHID(5, MPAD / 128);   // N=320
    const dim3 gMSG(2, MPAD / 128);   // N=128

    // ---- edge phase: message MLP + fused scatter, 16 chunks ----
    for (int c = 0; c < NCHUNK; ++c) {
        int e0 = c * CHUNK;
        build_tmp_bf16<<<(CHUNK * 64 + 255) / 256, 256, 0, stream>>>(x, ei, ea, tmp, e0);
        mfma_gemm<0, true ><<<gHID, 256, 0, stream>>>(tmp, mwt[0], mbp[0], hA, 64, 320, nullptr, 0);
        mfma_gemm<0, true ><<<gHID, 256, 0, stream>>>(hA,  mwt[1], mbp[1], hB, 320, 320, nullptr, 0);
        mfma_gemm<0, true ><<<gHID, 256, 0, stream>>>(hB,  mwt[2], mbp[2], hA, 320, 320, nullptr, 0);
        // msg layer: GEMM + bias + atomic scatter-add into aggr, fused
        mfma_gemm<2, false><<<gMSG, 256, 0, stream>>>(hA,  mwt[3], mbp[3], aggr, 320, 0,
                                                      ei + E_TOTAL + e0, CHUNK);
    }

    // ---- node phase ----
    cvt_aggr<<<(MPAD * 128 + 255) / 256, 256, 0, stream>>>(aggr, aggrb);
    mfma_gemm<0, true ><<<gHID, 256, 0, stream>>>(aggrb, nwt[0], nbp[0], hA, 128, 320, nullptr, 0);
    mfma_gemm<0, true ><<<gHID, 256, 0, stream>>>(hA,    nwt[1], nbp[1], hB, 320, 320, nullptr, 0);
    mfma_gemm<0, true ><<<gHID, 256, 0, stream>>>(hB,    nwt[2], nbp[2], hA, 320, 320, nullptr, 0);
    mfma_gemm<1, false><<<gHID, 256, 0, stream>>>(hA,    nwt[3], nbp[3], node, 320, 320, nullptr, 0);

    pool_kernel<<<dim3(64, 10), 256, 0, stream>>>(node, starts, pooled);
    final_kernel<<<1, 512, 0, stream>>>(pooled, lw, lb, out);
}

// Round 5
// 1066.246 us; speedup vs baseline: 2.2503x; 2.2503x over previous
//
#include <hip/hip_runtime.h>
#include <hip/hip_bf16.h>
#include <stdint.h>

// Problem constants
#define E_TOTAL 800000
#define NNODES  50000
#define NGRAPHS 64
#define NPRED   8
#define MPAD    50048          // node rows padded to 128 (391*128)
#define EBLK    6250           // 800000/128 edge blocks
#define NBLK    391            // MPAD/128 node blocks

// Weight tile stream: uniform 24 KB tiles = 384 rows (out-cols) x 32 k x bf16,
// stored pre-swizzled so linear global_load_lds yields the swizzled LDS image.
#define TILE_B  24576
#define SCR_W   10240          // per-wave scratch: 16 rows x 320 cols bf16 (640B rows)
#define LDSZ    (3*TILE_B + 8*SCR_W)   // 73728 + 81920 = 155648 <= 160K

typedef short v8s __attribute__((ext_vector_type(8)));
typedef float v4f __attribute__((ext_vector_type(4)));
typedef float f4  __attribute__((ext_vector_type(4)));

__device__ __forceinline__ void gload_lds16(const void* g, void* l) {
    __builtin_amdgcn_global_load_lds(
        (const __attribute__((address_space(1))) uint32_t*)g,
        (__attribute__((address_space(3))) uint32_t*)l, 16, 0, 0);
}

__device__ __forceinline__ short f2bf_s(float f) {
    __hip_bfloat16 h = __float2bfloat16(f);
    return *reinterpret_cast<short*>(&h);
}

// ---------------------------------------------------------------------------
// Fused MLP chain. EDGE: gather(x,ei,ea) -> L1(64) -> L2 -> L3 -> msg(128)
//                        -> atomic scatter into aggr.
//        !EDGE: aggrb(128) -> L1 -> L2 -> L3 -> L4(320) -> node fp32 store.
// 512 threads = 8 waves; wave owns 16 rows; acc = 20 x v4f (16x320 out).
// Weight tiles stream through a 3-slot LDS ring with counted vmcnt (loads for
// 2 future tiles stay in flight across barriers). Layer turnaround via
// per-wave swizzled LDS scratch (write C-layout, read A-frags).
// Protocol per tile: [stage(t+2); vmcnt(6); barrier; compute(t); barrier].
// ---------------------------------------------------------------------------
template <bool EDGE>
__global__ __launch_bounds__(512)
void chain_kernel(const float* __restrict__ x, const int* __restrict__ ei,
                  const float* __restrict__ ea,
                  const __hip_bfloat16* __restrict__ aggrb,
                  const char* __restrict__ wimg,
                  const float* __restrict__ b1, const float* __restrict__ b2,
                  const float* __restrict__ b3, const float* __restrict__ b4,
                  float* __restrict__ outp)
{
    __shared__ __align__(16) char lds[LDSZ];
    const int tid  = threadIdx.x;
    const int lane = tid & 63;
    const int wave = tid >> 6;
    const int l15  = lane & 15;   // A-row within wave / out-col within tile
    const int kk   = lane >> 4;   // 0..3 k-chunk / C row-group
    char* scr = lds + 3*TILE_B + wave*SCR_W;
    const int rowbase = blockIdx.x*128 + wave*16;

    constexpr int KT1 = EDGE ? 2 : 4;
    constexpr int T   = KT1 + 30;   // L1 tiles + 10+10+10

    auto stagef = [&](int t, int slot){
        const char* s = wimg + (size_t)t*TILE_B + (size_t)tid*16;
        char* d = lds + slot*TILE_B + wave*1024;   // wave-uniform dest (+lane*16 hw)
#pragma unroll
        for (int i = 0; i < 3; ++i) gload_lds16(s + i*8192, d + i*8192);
    };

    v4f acc[20];
#pragma unroll
    for (int n = 0; n < 20; ++n) acc[n] = (v4f){0.f,0.f,0.f,0.f};

    // ---- L1 A-fragments, built in registers (no build_tmp pass) ----
    v8s af[4];
    if (EDGE) {
        const int e = rowbase + l15;
        // k-block kk: 0,1 -> x[dst][0..7 / 8..15]; 2,3 -> x[src][0..7 / 8..15]
        const int nidx = (kk < 2) ? ei[E_TOTAL + e] : ei[e];
        const float* xs = x + (size_t)nidx*16 + (kk & 1)*8;
        f4 p0 = *(const f4*)xs;
        f4 p1 = *(const f4*)(xs + 4);
        v8s a0, a1;
#pragma unroll
        for (int j = 0; j < 4; ++j) { a0[j] = f2bf_s(p0[j]); a0[4+j] = f2bf_s(p1[j]); }
        if (kk == 0) {            // kb1: k 32..39 = edge_attr, rest zero
            const float* es = ea + (size_t)e*8;
            f4 q0 = *(const f4*)es, q1 = *(const f4*)(es + 4);
#pragma unroll
            for (int j = 0; j < 4; ++j) { a1[j] = f2bf_s(q0[j]); a1[4+j] = f2bf_s(q1[j]); }
        } else {
#pragma unroll
            for (int j = 0; j < 8; ++j) a1[j] = 0;
        }
        af[0] = a0; af[1] = a1; af[2] = a1; af[3] = a1;
    } else {
        const int grow = rowbase + l15;
#pragma unroll
        for (int kb = 0; kb < 4; ++kb)
            af[kb] = *(const v8s*)((const char*)aggrb + (size_t)grow*256 + kb*64 + kk*16);
    }

    stagef(0, 0); stagef(1, 1);
    int tt = 0, slot = 0;

    auto tilestep = [&](){
        if (tt + 2 < T) {
            stagef(tt + 2, (slot + 2) % 3);
            asm volatile("s_waitcnt vmcnt(6)" ::: "memory");
        } else if (tt + 1 < T) {
            asm volatile("s_waitcnt vmcnt(3)" ::: "memory");
        } else {
            asm volatile("s_waitcnt vmcnt(0)" ::: "memory");
        }
        __builtin_amdgcn_s_barrier();
    };
    auto tiledone = [&](){
        __builtin_amdgcn_s_barrier();
        tt++; slot = (slot + 1) % 3;
    };

// B-frag: row r = out-col, 64B rows, 16B chunk XOR ((r>>1)&3) (2-way max)
#define MFMA_TILE(A_, NT_)                                                     \
    {   const char* sl_ = lds + slot*TILE_B;                                   \
        _Pragma("unroll")                                                      \
        for (int n = 0; n < NT_; ++n) {                                        \
            int r_ = n*16 + l15;                                               \
            v8s b_ = *(const v8s*)(sl_ + r_*64 + ((kk ^ ((r_>>1)&3))<<4));     \
            acc[n] = __builtin_amdgcn_mfma_f32_16x16x32_bf16(A_, b_, acc[n], 0,0,0); \
        } }

// Dump acc (C layout: col=l15+n*16, row=kk*4+rr) -> scratch bf16 row-major
// 640B rows, 16B chunk XOR (row&7); then reset acc.
#define DUMP_RELU(BIAS_)                                                       \
    {   _Pragma("unroll")                                                      \
        for (int n = 0; n < 20; ++n) {                                         \
            int col_ = n*16 + l15;                                             \
            float bb_ = BIAS_[col_];                                           \
            _Pragma("unroll")                                                  \
            for (int rr = 0; rr < 4; ++rr) {                                   \
                int row_ = kk*4 + rr;                                          \
                float v_ = fmaxf(acc[n][rr] + bb_, 0.f);                       \
                *(__hip_bfloat16*)(scr + row_*640 +                            \
                    (((col_>>3) ^ (row_&7))<<4) + (col_&7)*2) = __float2bfloat16(v_); \
            }                                                                  \
            acc[n] = (v4f){0.f,0.f,0.f,0.f};                                   \
        } }

// A-frag from scratch: row=l15, k-chunk kc = kb*4+kk, same XOR
#define AFRAG(KB_) (*(const v8s*)(scr + l15*640 + ((((KB_)*4 + kk) ^ (l15 & 7))<<4)))

    // ---- L1 ----
#pragma unroll
    for (int kb = 0; kb < KT1; ++kb) { tilestep(); MFMA_TILE(af[kb], 20); tiledone(); }
    DUMP_RELU(b1);
    // ---- L2 ----
#pragma unroll
    for (int kb = 0; kb < 10; ++kb) { tilestep(); v8s a_ = AFRAG(kb); MFMA_TILE(a_, 20); tiledone(); }
    DUMP_RELU(b2);
    // ---- L3 ----
#pragma unroll
    for (int kb = 0; kb < 10; ++kb) { tilestep(); v8s a_ = AFRAG(kb); MFMA_TILE(a_, 20); tiledone(); }
    DUMP_RELU(b3);
    // ---- L4 ----
    if (EDGE) {
#pragma unroll
        for (int kb = 0; kb < 10; ++kb) { tilestep(); v8s a_ = AFRAG(kb); MFMA_TILE(a_, 8); tiledone(); }
        // fused scatter-add: aggr[dst[e]*128 + col] += msg
#pragma unroll
        for (int rr = 0; rr < 4; ++rr) {
            int erow = rowbase + kk*4 + rr;
            int d = ei[E_TOTAL + erow];
            float* ag = outp + (size_t)d*128;
#pragma unroll
            for (int n = 0; n < 8; ++n) {
                int col = n*16 + l15;
                atomicAdd(ag + col, acc[n][rr] + b4[col]);
            }
        }
    } else {
#pragma unroll
        for (int kb = 0; kb < 10; ++kb) { tilestep(); v8s a_ = AFRAG(kb); MFMA_TILE(a_, 20); tiledone(); }
        // store node fp32 [MPAD][320]
#pragma unroll
        for (int n = 0; n < 20; ++n) {
            int col = n*16 + l15;
            float bb = b4[col];
#pragma unroll
            for (int rr = 0; rr < 4; ++rr) {
                int grow = rowbase + kk*4 + rr;
                outp[(size_t)grow*320 + col] = acc[n][rr] + bb;
            }
        }
    }
#undef MFMA_TILE
#undef DUMP_RELU
#undef AFRAG
}

// ---------------------------------------------------------------------------
// Repack fp32 W [K][N] -> pre-swizzled bf16 tile stream (KT tiles of 384x32)
// ---------------------------------------------------------------------------
__global__ void repack_tiles(const float* __restrict__ src, char* __restrict__ img,
                             int K, int N, int KT)
{
    int t = blockIdx.x*256 + threadIdx.x;
    if (t >= KT*12288) return;
    int k32 = t & 31;
    int r5  = t >> 5;
    int kb  = r5 / 384;
    int n   = r5 - kb*384;
    int kg  = kb*32 + k32;
    float v = (n < N && kg < K) ? src[(size_t)kg*N + n] : 0.f;
    size_t addr = (size_t)kb*TILE_B + (size_t)n*64 +
                  (((k32>>3) ^ ((n>>1)&3))<<4) + (k32&7)*2;
    *(__hip_bfloat16*)(img + addr) = __float2bfloat16(v);
}

__global__ void pad_bias(const float* __restrict__ src, float* __restrict__ dst,
                         int N, int Npad)
{
    int t = blockIdx.x*256 + threadIdx.x;
    if (t < Npad) dst[t] = (t < N) ? src[t] : 0.f;
}

// aggr fp32 [MPAD][128] -> bf16 (rows >= NNODES forced to 0)
__global__ void cvt_aggr(const float* __restrict__ aggr, __hip_bfloat16* __restrict__ out)
{
    int t = blockIdx.x*256 + threadIdx.x;
    int row = t >> 7;
    float v = (row < NNODES) ? aggr[t] : 0.f;
    out[t] = __float2bfloat16(v);
}

__global__ void graph_starts_kernel(const int* __restrict__ batch,
                                    int* __restrict__ starts)
{
    int g = threadIdx.x;
    if (g > NGRAPHS) return;
    int lo = 0, hi = NNODES;
    while (lo < hi) {
        int mid = (lo + hi) >> 1;
        if (batch[mid] < g) lo = mid + 1; else hi = mid;
    }
    starts[g] = lo;
}

// Mean pool: node fp32 [MPAD][320] (valid cols 0..299) -> pooled [64][300]
__global__ void pool_kernel(const float* __restrict__ node,
                            const int* __restrict__ starts,
                            float* __restrict__ pooled)
{
    __shared__ float red[8][32];
    int g   = blockIdx.x;
    int col = blockIdx.y*32 + (threadIdx.x & 31);
    int rl  = threadIdx.x >> 5;
    int s = starts[g], e = starts[g + 1];
    float sum = 0.f;
    if (col < 300)
        for (int i = s + rl; i < e; i += 8) sum += node[(size_t)i*320 + col];
    red[rl][threadIdx.x & 31] = sum;
    __syncthreads();
    if (rl == 0 && col < 300) {
        float tot = 0.f;
#pragma unroll
        for (int r = 0; r < 8; ++r) tot += red[r][threadIdx.x & 31];
        float cnt = (float)(e - s);
        pooled[g*300 + col] = tot / fmaxf(cnt, 1.0f);
    }
}

__global__ void final_kernel(const float* __restrict__ pooled,
                             const float* __restrict__ lw,
                             const float* __restrict__ lb,
                             float* __restrict__ out)
{
    int t = threadIdx.x;          // 512 = 64 * 8
    int g = t / NPRED, p = t % NPRED;
    float s = lb[p];
    for (int k = 0; k < 300; ++k)
        s = fmaf(pooled[g*300 + k], lw[k*NPRED + p], s);
    out[g*NPRED + p] = s;
}

// ---------------------------------------------------------------------------
extern "C" void kernel_launch(void* const* d_in, const int* in_sizes, int n_in,
                              void* d_out, int out_size, void* d_ws, size_t ws_size,
                              hipStream_t stream)
{
    const float* x     = (const float*)d_in[0];
    const int*   ei    = (const int*)d_in[1];
    const float* ea    = (const float*)d_in[2];
    const int*   batch = (const int*)d_in[3];
    const float* mw[4] = {(const float*)d_in[4], (const float*)d_in[6],
                          (const float*)d_in[8], (const float*)d_in[10]};
    const float* mb[4] = {(const float*)d_in[5], (const float*)d_in[7],
                          (const float*)d_in[9], (const float*)d_in[11]};
    const float* nw[4] = {(const float*)d_in[12], (const float*)d_in[14],
                          (const float*)d_in[16], (const float*)d_in[18]};
    const float* nb[4] = {(const float*)d_in[13], (const float*)d_in[15],
                          (const float*)d_in[17], (const float*)d_in[19]};
    const float* lw = (const float*)d_in[20];
    const float* lb = (const float*)d_in[21];
    float* out = (float*)d_out;

    char* ws = (char*)d_ws;
    size_t off = 0;
    auto alloc = [&](size_t bytes) -> void* {
        void* p = ws + off;
        off += (bytes + 255) & ~(size_t)255;
        return p;
    };

    float*          aggr   = (float*)alloc((size_t)MPAD*128*4);          // 25.6 MB
    __hip_bfloat16* aggrb  = (__hip_bfloat16*)alloc((size_t)MPAD*128*2); // 12.8 MB
    float*          node   = (float*)alloc((size_t)MPAD*320*4);          // 64.1 MB
    char*           wimg_e = (char*)alloc((size_t)32*TILE_B);            // 768 KB
    char*           wimg_n = (char*)alloc((size_t)34*TILE_B);            // 816 KB
    float* mbp[4]; float* nbp[4];
    for (int i = 0; i < 4; ++i) { mbp[i] = (float*)alloc(320*4); nbp[i] = (float*)alloc(320*4); }
    float* pooled = (float*)alloc(64*300*4);
    int*   starts = (int*)alloc(65*4);

    // ---- weight repack into pre-swizzled tile streams ----
    const int mK[4] = {40, 300, 300, 300},  mN[4] = {300, 300, 300, 128};
    const int nK[4] = {128, 300, 300, 300}, nN[4] = {300, 300, 300, 300};
    const int mKT[4] = {2, 10, 10, 10},     nKT[4] = {4, 10, 10, 10};
    {
        size_t te = 0, tn = 0;
        for (int i = 0; i < 4; ++i) {
            repack_tiles<<<mKT[i]*48, 256, 0, stream>>>(mw[i], wimg_e + te*TILE_B,
                                                        mK[i], mN[i], mKT[i]);
            te += mKT[i];
            repack_tiles<<<nKT[i]*48, 256, 0, stream>>>(nw[i], wimg_n + tn*TILE_B,
                                                        nK[i], nN[i], nKT[i]);
            tn += nKT[i];
            pad_bias<<<2, 256, 0, stream>>>(mb[i], mbp[i], mN[i], 320);
            pad_bias<<<2, 256, 0, stream>>>(nb[i], nbp[i], nN[i], 320);
        }
    }
    hipMemsetAsync(aggr, 0, (size_t)NNODES*128*4, stream);
    graph_starts_kernel<<<1, 128, 0, stream>>>(batch, starts);

    // ---- edge phase: ONE kernel for all 800K edges ----
    chain_kernel<true><<<EBLK, 512, 0, stream>>>(
        x, ei, ea, nullptr, wimg_e, mbp[0], mbp[1], mbp[2], mbp[3], aggr);

    // ---- node phase ----
    cvt_aggr<<<(MPAD*128)/256, 256, 0, stream>>>(aggr, aggrb);
    chain_kernel<false><<<NBLK, 512, 0, stream>>>(
        x, ei, ea, aggrb, wimg_n, nbp[0], nbp[1], nbp[2], nbp[3], node);

    pool_kernel<<<dim3(64, 10), 256, 0, stream>>>(node, starts, pooled);
    final_kernel<<<1, 512, 0, stream>>>(pooled, lw, lb, out);
}

// Round 6
// 832.891 us; speedup vs baseline: 2.8808x; 1.2802x over previous
//
#include <hip/hip_runtime.h>
#include <hip/hip_bf16.h>
#include <stdint.h>

// Problem constants
#define E_TOTAL 800000
#define NNODES  50000
#define NGRAPHS 64
#define NPRED   8
#define MPAD    50048          // node rows padded to 128 (391*128)
#define EBLK    6250           // 800000/128 edge blocks
#define NBLK    391            // MPAD/128 node blocks

// Weight tile stream: uniform 24 KB tiles = 384 rows (out-cols) x 32 k x bf16,
// stored pre-swizzled so linear global_load_lds yields the swizzled LDS image.
#define TILE_B  24576
#define SCR_B   81920          // block-shared scratch: 128 rows x 320 cols bf16 (640B rows)
#define LDSZ    (3*TILE_B + SCR_B)   // 73728 + 81920 = 155648 <= 160K

typedef short v8s __attribute__((ext_vector_type(8)));
typedef float v4f __attribute__((ext_vector_type(4)));
typedef float f4  __attribute__((ext_vector_type(4)));

__device__ __forceinline__ void gload_lds16(const void* g, void* l) {
    __builtin_amdgcn_global_load_lds(
        (const __attribute__((address_space(1))) uint32_t*)g,
        (__attribute__((address_space(3))) uint32_t*)l, 16, 0, 0);
}

__device__ __forceinline__ short f2bf_s(float f) {
    __hip_bfloat16 h = __float2bfloat16(f);
    return *reinterpret_cast<short*>(&h);
}

// ---------------------------------------------------------------------------
// Fused MLP chain. EDGE: gather(x,ei,ea) -> L1(64) -> L2 -> L3 -> msg(128)
//                        -> atomic scatter into aggr.
//        !EDGE: aggrb(128) -> L1 -> L2 -> L3 -> L4(320) -> node fp32 store.
// 512 threads = 8 waves in a 4x2 grid: wave (wr,wc) owns 32 rows x 160 cols
// (2 row-panels of 16). Per k-tile: 10 B-frag + 2 A-frag LDS reads for 20
// MFMAs (reads/MFMA = 0.6, vs 1.05 in the 16-rows-per-wave layout).
// acc = 2x10 v4f (80 VGPR). Weight tiles stream through a 3-slot LDS ring
// with counted vmcnt(6) (2 future tiles in flight across barriers).
// Layer turnaround via block-shared swizzled LDS scratch (write C-layout,
// read A-frags); DUMP ends with lgkmcnt(0) so the cross-wave barrier is safe.
// ---------------------------------------------------------------------------
template <bool EDGE>
__global__ __launch_bounds__(512)
void chain_kernel(const float* __restrict__ x, const int* __restrict__ ei,
                  const float* __restrict__ ea,
                  const __hip_bfloat16* __restrict__ aggrb,
                  const char* __restrict__ wimg,
                  const float* __restrict__ b1, const float* __restrict__ b2,
                  const float* __restrict__ b3, const float* __restrict__ b4,
                  float* __restrict__ outp)
{
    __shared__ __align__(16) char lds[LDSZ];
    const int tid  = threadIdx.x;
    const int lane = tid & 63;
    const int wave = tid >> 6;
    const int wr   = wave >> 1;   // 0..3 row quarter (32 rows)
    const int wc   = wave & 1;    // 0..1 col half (160 cols)
    const int l15  = lane & 15;
    const int kk   = lane >> 4;   // 0..3
    char* scr = lds + 3*TILE_B;   // block-shared scratch
    const int rowbase = blockIdx.x*128 + wr*32;

    constexpr int KT1 = EDGE ? 2 : 4;
    constexpr int T   = KT1 + 30;   // L1 tiles + 10+10+10

    auto stagef = [&](int t, int slot){
        const char* s = wimg + (size_t)t*TILE_B + (size_t)tid*16;
        char* d = lds + slot*TILE_B + wave*1024;   // wave-uniform dest (+lane*16 hw)
#pragma unroll
        for (int i = 0; i < 3; ++i) gload_lds16(s + i*8192, d + i*8192);
    };

    v4f acc[2][10];
#pragma unroll
    for (int p = 0; p < 2; ++p)
#pragma unroll
        for (int n = 0; n < 10; ++n) acc[p][n] = (v4f){0.f,0.f,0.f,0.f};

    // ---- L1 A-fragments for both panels, built in registers ----
    v8s af[2][4];
#pragma unroll
    for (int p = 0; p < 2; ++p) {
        if (EDGE) {
            const int e = rowbase + p*16 + l15;
            // kb0: kk 0,1 -> x[dst][0..7/8..15]; kk 2,3 -> x[src][0..7/8..15]
            const int nidx = (kk < 2) ? ei[E_TOTAL + e] : ei[e];
            const float* xs = x + (size_t)nidx*16 + (kk & 1)*8;
            f4 p0 = *(const f4*)xs;
            f4 p1 = *(const f4*)(xs + 4);
            v8s a0, a1;
#pragma unroll
            for (int j = 0; j < 4; ++j) { a0[j] = f2bf_s(p0[j]); a0[4+j] = f2bf_s(p1[j]); }
            if (kk == 0) {            // kb1: k 32..39 = edge_attr, rest zero
                const float* es = ea + (size_t)e*8;
                f4 q0 = *(const f4*)es, q1 = *(const f4*)(es + 4);
#pragma unroll
                for (int j = 0; j < 4; ++j) { a1[j] = f2bf_s(q0[j]); a1[4+j] = f2bf_s(q1[j]); }
            } else {
#pragma unroll
                for (int j = 0; j < 8; ++j) a1[j] = 0;
            }
            af[p][0] = a0; af[p][1] = a1; af[p][2] = a1; af[p][3] = a1;
        } else {
            const int grow = rowbase + p*16 + l15;
#pragma unroll
            for (int kb = 0; kb < 4; ++kb)
                af[p][kb] = *(const v8s*)((const char*)aggrb + (size_t)grow*256 + kb*64 + kk*16);
        }
    }

    stagef(0, 0); stagef(1, 1);
    int tt = 0, slot = 0;

    auto tilestep = [&](){
        if (tt + 2 < T) {
            stagef(tt + 2, (slot + 2) % 3);
            asm volatile("s_waitcnt vmcnt(6)" ::: "memory");
        } else if (tt + 1 < T) {
            asm volatile("s_waitcnt vmcnt(3)" ::: "memory");
        } else {
            asm volatile("s_waitcnt vmcnt(0)" ::: "memory");
        }
        __builtin_amdgcn_s_barrier();
    };
    auto tiledone = [&](){
        __builtin_amdgcn_s_barrier();
        tt++; slot = (slot + 1) % 3;
    };

// B-frag: row r = out-col, 64B rows, 16B chunk XOR ((r>>1)&3) (matches repack)
#define MFMA_TILE2(A0_, A1_, NT_, CB_)                                         \
    {   const char* sl_ = lds + slot*TILE_B;                                   \
        _Pragma("unroll")                                                      \
        for (int n = 0; n < NT_; ++n) {                                        \
            int r_ = (CB_) + n*16 + l15;                                       \
            v8s b_ = *(const v8s*)(sl_ + r_*64 + ((kk ^ ((r_>>1)&3))<<4));     \
            acc[0][n] = __builtin_amdgcn_mfma_f32_16x16x32_bf16(A0_, b_, acc[0][n], 0,0,0); \
            acc[1][n] = __builtin_amdgcn_mfma_f32_16x16x32_bf16(A1_, b_, acc[1][n], 0,0,0); \
        } }

// Dump acc (C layout: col=l15+n*16+wc*160, row=wr*32+p*16+kk*4+rr) -> shared
// scratch bf16, 640B rows, 16B chunk XOR (row&7); reset acc; drain writes.
#define DUMP_RELU(BIAS_)                                                       \
    {   _Pragma("unroll")                                                      \
        for (int p = 0; p < 2; ++p) {                                          \
            _Pragma("unroll")                                                  \
            for (int n = 0; n < 10; ++n) {                                     \
                int col_ = wc*160 + n*16 + l15;                                \
                float bb_ = BIAS_[col_];                                       \
                _Pragma("unroll")                                              \
                for (int rr = 0; rr < 4; ++rr) {                               \
                    int row_ = wr*32 + p*16 + kk*4 + rr;                       \
                    float v_ = fmaxf(acc[p][n][rr] + bb_, 0.f);                \
                    *(__hip_bfloat16*)(scr + row_*640 +                        \
                        (((col_>>3) ^ (row_&7))<<4) + (col_&7)*2) = __float2bfloat16(v_); \
                }                                                              \
                acc[p][n] = (v4f){0.f,0.f,0.f,0.f};                            \
            }                                                                  \
        }                                                                      \
        asm volatile("s_waitcnt lgkmcnt(0)" ::: "memory");                     \
    }

// A-frag from scratch: row = wr*32 + p*16 + l15, k-chunk kb*4+kk, same XOR
#define AFRAG(P_, KB_) (*(const v8s*)(scr + (wr*32 + (P_)*16 + l15)*640 +      \
                          ((((KB_)*4 + kk) ^ (l15 & 7))<<4)))

    // ---- L1 ----
#pragma unroll
    for (int kb = 0; kb < KT1; ++kb) {
        tilestep(); MFMA_TILE2(af[0][kb], af[1][kb], 10, wc*160); tiledone();
    }
    DUMP_RELU(b1);
    // ---- L2 ----
#pragma unroll
    for (int kb = 0; kb < 10; ++kb) {
        tilestep();
        v8s a0_ = AFRAG(0, kb), a1_ = AFRAG(1, kb);
        MFMA_TILE2(a0_, a1_, 10, wc*160); tiledone();
    }
    DUMP_RELU(b2);
    // ---- L3 ----
#pragma unroll
    for (int kb = 0; kb < 10; ++kb) {
        tilestep();
        v8s a0_ = AFRAG(0, kb), a1_ = AFRAG(1, kb);
        MFMA_TILE2(a0_, a1_, 10, wc*160); tiledone();
    }
    DUMP_RELU(b3);
    // ---- L4 ----
    if (EDGE) {
#pragma unroll
        for (int kb = 0; kb < 10; ++kb) {
            tilestep();
            v8s a0_ = AFRAG(0, kb), a1_ = AFRAG(1, kb);
            MFMA_TILE2(a0_, a1_, 4, wc*64); tiledone();
        }
        // fused scatter-add: aggr[dst[e]*128 + col] += msg
#pragma unroll
        for (int p = 0; p < 2; ++p) {
#pragma unroll
            for (int rr = 0; rr < 4; ++rr) {
                int erow = rowbase + p*16 + kk*4 + rr;
                int d = ei[E_TOTAL + erow];
                float* ag = outp + (size_t)d*128 + wc*64;
#pragma unroll
                for (int n = 0; n < 4; ++n) {
                    int col = n*16 + l15;
                    atomicAdd(ag + col, acc[p][n][rr] + b4[wc*64 + col]);
                }
            }
        }
    } else {
#pragma unroll
        for (int kb = 0; kb < 10; ++kb) {
            tilestep();
            v8s a0_ = AFRAG(0, kb), a1_ = AFRAG(1, kb);
            MFMA_TILE2(a0_, a1_, 10, wc*160); tiledone();
        }
        // store node fp32 [MPAD][320]
#pragma unroll
        for (int p = 0; p < 2; ++p) {
#pragma unroll
            for (int n = 0; n < 10; ++n) {
                int col = wc*160 + n*16 + l15;
                float bb = b4[col];
#pragma unroll
                for (int rr = 0; rr < 4; ++rr) {
                    int grow = rowbase + p*16 + kk*4 + rr;
                    outp[(size_t)grow*320 + col] = acc[p][n][rr] + bb;
                }
            }
        }
    }
#undef MFMA_TILE2
#undef DUMP_RELU
#undef AFRAG
}

// ---------------------------------------------------------------------------
// Repack fp32 W [K][N] -> pre-swizzled bf16 tile stream (KT tiles of 384x32)
// ---------------------------------------------------------------------------
__global__ void repack_tiles(const float* __restrict__ src, char* __restrict__ img,
                             int K, int N, int KT)
{
    int t = blockIdx.x*256 + threadIdx.x;
    if (t >= KT*12288) return;
    int k32 = t & 31;
    int r5  = t >> 5;
    int kb  = r5 / 384;
    int n   = r5 - kb*384;
    int kg  = kb*32 + k32;
    float v = (n < N && kg < K) ? src[(size_t)kg*N + n] : 0.f;
    size_t addr = (size_t)kb*TILE_B + (size_t)n*64 +
                  (((k32>>3) ^ ((n>>1)&3))<<4) + (k32&7)*2;
    *(__hip_bfloat16*)(img + addr) = __float2bfloat16(v);
}

__global__ void pad_bias(const float* __restrict__ src, float* __restrict__ dst,
                         int N, int Npad)
{
    int t = blockIdx.x*256 + threadIdx.x;
    if (t < Npad) dst[t] = (t < N) ? src[t] : 0.f;
}

// aggr fp32 [MPAD][128] -> bf16 (rows >= NNODES forced to 0)
__global__ void cvt_aggr(const float* __restrict__ aggr, __hip_bfloat16* __restrict__ out)
{
    int t = blockIdx.x*256 + threadIdx.x;
    int row = t >> 7;
    float v = (row < NNODES) ? aggr[t] : 0.f;
    out[t] = __float2bfloat16(v);
}

__global__ void graph_starts_kernel(const int* __restrict__ batch,
                                    int* __restrict__ starts)
{
    int g = threadIdx.x;
    if (g > NGRAPHS) return;
    int lo = 0, hi = NNODES;
    while (lo < hi) {
        int mid = (lo + hi) >> 1;
        if (batch[mid] < g) lo = mid + 1; else hi = mid;
    }
    starts[g] = lo;
}

// Mean pool: node fp32 [MPAD][320] (valid cols 0..299) -> pooled [64][300]
__global__ void pool_kernel(const float* __restrict__ node,
                            const int* __restrict__ starts,
                            float* __restrict__ pooled)
{
    __shared__ float red[8][32];
    int g   = blockIdx.x;
    int col = blockIdx.y*32 + (threadIdx.x & 31);
    int rl  = threadIdx.x >> 5;
    int s = starts[g], e = starts[g + 1];
    float sum = 0.f;
    if (col < 300)
        for (int i = s + rl; i < e; i += 8) sum += node[(size_t)i*320 + col];
    red[rl][threadIdx.x & 31] = sum;
    __syncthreads();
    if (rl == 0 && col < 300) {
        float tot = 0.f;
#pragma unroll
        for (int r = 0; r < 8; ++r) tot += red[r][threadIdx.x & 31];
        float cnt = (float)(e - s);
        pooled[g*300 + col] = tot / fmaxf(cnt, 1.0f);
    }
}

__global__ void final_kernel(const float* __restrict__ pooled,
                             const float* __restrict__ lw,
                             const float* __restrict__ lb,
                             float* __restrict__ out)
{
    int t = threadIdx.x;          // 512 = 64 * 8
    int g = t / NPRED, p = t % NPRED;
    float s = lb[p];
    for (int k = 0; k < 300; ++k)
        s = fmaf(pooled[g*300 + k], lw[k*NPRED + p], s);
    out[g*NPRED + p] = s;
}

// ---------------------------------------------------------------------------
extern "C" void kernel_launch(void* const* d_in, const int* in_sizes, int n_in,
                              void* d_out, int out_size, void* d_ws, size_t ws_size,
                              hipStream_t stream)
{
    const float* x     = (const float*)d_in[0];
    const int*   ei    = (const int*)d_in[1];
    const float* ea    = (const float*)d_in[2];
    const int*   batch = (const int*)d_in[3];
    const float* mw[4] = {(const float*)d_in[4], (const float*)d_in[6],
                          (const float*)d_in[8], (const float*)d_in[10]};
    const float* mb[4] = {(const float*)d_in[5], (const float*)d_in[7],
                          (const float*)d_in[9], (const float*)d_in[11]};
    const float* nw[4] = {(const float*)d_in[12], (const float*)d_in[14],
                          (const float*)d_in[16], (const float*)d_in[18]};
    const float* nb[4] = {(const float*)d_in[13], (const float*)d_in[15],
                          (const float*)d_in[17], (const float*)d_in[19]};
    const float* lw = (const float*)d_in[20];
    const float* lb = (const float*)d_in[21];
    float* out = (float*)d_out;

    char* ws = (char*)d_ws;
    size_t off = 0;
    auto alloc = [&](size_t bytes) -> void* {
        void* p = ws + off;
        off += (bytes + 255) & ~(size_t)255;
        return p;
    };

    float*          aggr   = (float*)alloc((size_t)MPAD*128*4);          // 25.6 MB
    __hip_bfloat16* aggrb  = (__hip_bfloat16*)alloc((size_t)MPAD*128*2); // 12.8 MB
    float*          node   = (float*)alloc((size_t)MPAD*320*4);          // 64.1 MB
    char*           wimg_e = (char*)alloc((size_t)32*TILE_B);            // 768 KB
    char*           wimg_n = (char*)alloc((size_t)34*TILE_B);            // 816 KB
    float* mbp[4]; float* nbp[4];
    for (int i = 0; i < 4; ++i) { mbp[i] = (float*)alloc(320*4); nbp[i] = (float*)alloc(320*4); }
    float* pooled = (float*)alloc(64*300*4);
    int*   starts = (int*)alloc(65*4);

    // ---- weight repack into pre-swizzled tile streams ----
    const int mK[4] = {40, 300, 300, 300},  mN[4] = {300, 300, 300, 128};
    const int nK[4] = {128, 300, 300, 300}, nN[4] = {300, 300, 300, 300};
    const int mKT[4] = {2, 10, 10, 10},     nKT[4] = {4, 10, 10, 10};
    {
        size_t te = 0, tn = 0;
        for (int i = 0; i < 4; ++i) {
            repack_tiles<<<mKT[i]*48, 256, 0, stream>>>(mw[i], wimg_e + te*TILE_B,
                                                        mK[i], mN[i], mKT[i]);
            te += mKT[i];
            repack_tiles<<<nKT[i]*48, 256, 0, stream>>>(nw[i], wimg_n + tn*TILE_B,
                                                        nK[i], nN[i], nKT[i]);
            tn += nKT[i];
            pad_bias<<<2, 256, 0, stream>>>(mb[i], mbp[i], mN[i], 320);
            pad_bias<<<2, 256, 0, stream>>>(nb[i], nbp[i], nN[i], 320);
        }
    }
    hipMemsetAsync(aggr, 0, (size_t)NNODES*128*4, stream);
    graph_starts_kernel<<<1, 128, 0, stream>>>(batch, starts);

    // ---- edge phase: ONE kernel for all 800K edges ----
    chain_kernel<true><<<EBLK, 512, 0, stream>>>(
        x, ei, ea, nullptr, wimg_e, mbp[0], mbp[1], mbp[2], mbp[3], aggr);

    // ---- node phase ----
    cvt_aggr<<<(MPAD*128)/256, 256, 0, stream>>>(aggr, aggrb);
    chain_kernel<false><<<NBLK, 512, 0, stream>>>(
        x, ei, ea, aggrb, wimg_n, nbp[0], nbp[1], nbp[2], nbp[3], node);

    pool_kernel<<<dim3(64, 10), 256, 0, stream>>>(node, starts, pooled);
    final_kernel<<<1, 512, 0, stream>>>(pooled, lw, lb, out);
}